// Round 4
// baseline (3598.938 us; speedup 1.0000x reference)
//
#include <hip/hip_runtime.h>
#include <math.h>

#define NN 50000
#define EE 1600000
#define FN 92
#define FE 41
#define CC 128
#define LL 3
#define GG 256
#define ZDIM 297   // 2C + F_EDGE
#define NCHUNK (EE / 16)

typedef __attribute__((ext_vector_type(8))) short s8v;   // 8 bf16 (4 VGPRs)
typedef __attribute__((ext_vector_type(4))) float f4v;   // MFMA C/D

__device__ __forceinline__ float softplus_f(float x) {
    float e = __expf(-fabsf(x));
    return fmaxf(x, 0.0f) + __logf(1.0f + e);
}
__device__ __forceinline__ float sigmoid_f(float x) {
    return __builtin_amdgcn_rcpf(1.0f + __expf(-x));
}
__device__ __forceinline__ unsigned short f2bf(float x) {   // RNE fp32->bf16
    unsigned u = __builtin_bit_cast(unsigned, x);
    unsigned r = u + 0x7fffu + ((u >> 16) & 1u);
    return (unsigned short)(r >> 16);
}
__device__ __forceinline__ float bflo2f(unsigned u) {
    return __builtin_bit_cast(float, u << 16);
}
__device__ __forceinline__ float bfhi2f(unsigned u) {
    return __builtin_bit_cast(float, u & 0xffff0000u);
}

// ---------------------------------------------------------------------------
// fp32 tiled GEMM: C = act(A[M][lda](K used) @ B[Kpad][NC] + bias)
// OUTBF=1: write bf16 pairs (adjacent columns packed into uint).
// ---------------------------------------------------------------------------
template<int ACT, int OUTBF>
__global__ __launch_bounds__(256)
void gemm_rt(const float* __restrict__ A, const float* __restrict__ B,
             float* __restrict__ C, const float* __restrict__ bias,
             int M, int K, int lda, int NC) {
    __shared__ float As[32][68];
    __shared__ float Bs[32 * 128];
    int tid = threadIdx.x;
    int colTiles = NC >> 7;
    int rowTile = blockIdx.x / colTiles;
    int colTile = blockIdx.x - rowTile * colTiles;
    int row0 = rowTile * 64;
    int c0 = colTile * 128;
    int ty = tid >> 5;
    int tx = tid & 31;

    float acc[8][4];
#pragma unroll
    for (int i = 0; i < 8; i++)
#pragma unroll
        for (int j = 0; j < 4; j++) acc[i][j] = 0.f;

    int nChunks = (K + 31) >> 5;
    for (int ch = 0; ch < nChunks; ch++) {
        int k0 = ch << 5;
#pragma unroll
        for (int t = 0; t < 8; t++) {
            int idx = tid + t * 256;
            int r = idx >> 5;
            int kk = idx & 31;
            int grow = row0 + r;
            int gk = k0 + kk;
            float v = 0.f;
            if (grow < M && gk < K) v = A[(long)grow * lda + gk];
            As[kk][r] = v;
        }
        const float* Bg = B + (long)k0 * NC + c0;
#pragma unroll
        for (int t = 0; t < 4; t++) {
            int f4 = tid + t * 256;
            int kk = f4 >> 5;
            int j = (f4 & 31) << 2;
            float4 v = *(const float4*)(Bg + (long)kk * NC + j);
            *(float4*)(&Bs[kk * 128 + j]) = v;
        }
        __syncthreads();
#pragma unroll
        for (int kk = 0; kk < 32; kk++) {
            float4 a0 = *(const float4*)(&As[kk][ty * 8]);
            float4 a1 = *(const float4*)(&As[kk][ty * 8 + 4]);
            float4 b  = *(const float4*)(&Bs[kk * 128 + tx * 4]);
            float av[8] = {a0.x, a0.y, a0.z, a0.w, a1.x, a1.y, a1.z, a1.w};
            float bv[4] = {b.x, b.y, b.z, b.w};
#pragma unroll
            for (int i = 0; i < 8; i++)
#pragma unroll
                for (int j = 0; j < 4; j++)
                    acc[i][j] = fmaf(av[i], bv[j], acc[i][j]);
        }
        __syncthreads();
    }
    float bv[4] = {0.f, 0.f, 0.f, 0.f};
    if (bias) {
#pragma unroll
        for (int j = 0; j < 4; j++) bv[j] = bias[c0 + tx * 4 + j];
    }
#pragma unroll
    for (int i = 0; i < 8; i++) {
        int grow = row0 + ty * 8 + i;
        if (grow < M) {
            float r0 = acc[i][0] + bv[0];
            float r1 = acc[i][1] + bv[1];
            float r2 = acc[i][2] + bv[2];
            float r3 = acc[i][3] + bv[3];
            if (ACT) { r0 = softplus_f(r0); r1 = softplus_f(r1);
                       r2 = softplus_f(r2); r3 = softplus_f(r3); }
            if (OUTBF) {
                unsigned u0 = (unsigned)f2bf(r0) | ((unsigned)f2bf(r1) << 16);
                unsigned u1 = (unsigned)f2bf(r2) | ((unsigned)f2bf(r3) << 16);
                uint2 val; val.x = u0; val.y = u1;
                unsigned short* Cb = (unsigned short*)C;
                *(uint2*)(Cb + (long)grow * NC + c0 + tx * 4) = val;
            } else {
                float4 o; o.x = r0; o.y = r1; o.z = r2; o.w = r3;
                *(float4*)(&C[(long)grow * NC + c0 + tx * 4]) = o;
            }
        }
    }
}

// WB[k][j]: j = 2*(blk*128 + q) + g, where g: 0=Wf,1=Ws; blk: 0=dst(x_i) cols,
// 1=src(x_j) cols; q = perm(c) = (c&15)*8 + (c>>4)  (so lane loads are uint4).
__global__ void build_WB(const float* __restrict__ Wf, const float* __restrict__ Ws,
                         float* __restrict__ WB) {
    int idx = blockIdx.x * blockDim.x + threadIdx.x;
    if (idx >= 128 * 512) return;
    int k = idx >> 9;
    int j = idx & 511;
    int g = j & 1;
    int pos = j >> 1;
    int blk = pos >> 7;
    int q = pos & 127;
    int c = (q >> 3) | ((q & 7) << 4);   // inverse perm
    const float* W = g ? Ws : Wf;
    WB[idx] = W[c * ZDIM + blk * 128 + k];
}

// WE[l][g][c][k] bf16, k<41: edge-weight col, k==41: bias, else 0. K padded to 64.
__global__ void build_WE(const float* __restrict__ Wf, const float* __restrict__ Ws,
                         const float* __restrict__ bf, const float* __restrict__ bs,
                         unsigned short* __restrict__ WE) {
    int idx = blockIdx.x * blockDim.x + threadIdx.x;
    if (idx >= LL * 2 * 128 * 64) return;
    int k = idx & 63;
    int c = (idx >> 6) & 127;
    int g = (idx >> 13) & 1;
    int l = idx >> 14;
    const float* W = g ? Ws : Wf;
    const float* b = g ? bs : bf;
    float v = 0.f;
    if (k < FE) v = W[((long)l * 128 + c) * ZDIM + 256 + k];
    else if (k == FE) v = b[l * 128 + c];
    WE[idx] = f2bf(v);
}

// WT[Kpad][C] = W[C][K]^T zero-padded
__global__ void transpose_pad(const float* __restrict__ W, float* __restrict__ WT,
                              int C_, int K_, int Kpad) {
    int idx = blockIdx.x * blockDim.x + threadIdx.x;
    if (idx >= Kpad * C_) return;
    int k = idx / C_;
    int c = idx - k * C_;
    WT[idx] = (k < K_) ? W[c * K_ + k] : 0.f;
}

// Pack ea into MFMA A-fragment layout, bf16, bias column k=41 folded in.
// eap[(chunk*64 + lane)*16 + 0..15] : a0 (k=quad*8..+7), a1 (k=32+quad*8..+7)
__global__ void pack_ea(const float* __restrict__ ea, unsigned short* __restrict__ eap) {
    long t = (long)blockIdx.x * blockDim.x + threadIdx.x;
    if (t >= (long)NCHUNK * 64) return;
    int lane = (int)(t & 63);
    long chk = t >> 6;
    int quad = lane >> 4, l16 = lane & 15;
    const float* ar = ea + (chk * 16 + l16) * (long)FE;
    unsigned short o[16];
#pragma unroll
    for (int j = 0; j < 8; j++) o[j] = f2bf(ar[quad * 8 + j]);
#pragma unroll
    for (int j = 0; j < 8; j++) {
        int k1 = 32 + quad * 8 + j;
        float v = 0.f;
        if (k1 < FE) v = ar[k1];
        else if (k1 == FE) v = 1.0f;
        o[8 + j] = f2bf(v);
    }
    uint4* dst = (uint4*)(eap + t * 16);
    uint4 w0, w1;
    w0.x = o[0] | ((unsigned)o[1] << 16);  w0.y = o[2] | ((unsigned)o[3] << 16);
    w0.z = o[4] | ((unsigned)o[5] << 16);  w0.w = o[6] | ((unsigned)o[7] << 16);
    w1.x = o[8] | ((unsigned)o[9] << 16);  w1.y = o[10] | ((unsigned)o[11] << 16);
    w1.z = o[12] | ((unsigned)o[13] << 16); w1.w = o[14] | ((unsigned)o[15] << 16);
    dst[0] = w0; dst[1] = w1;
}

// ---------------------------------------------------------------------------
// Fused edge kernel. Each wave: 16 consecutive edges.
//  Phase 1: Qf,Qs = [16x48 ea+bias] @ WE^T via 32 MFMAs.
//  Phase 2: P rows stored bf16 (f,s)-packed with perm'd channel order so each
//  lane reads its 8 pairs as 2x dwordx4; gate in registers; atomic scatter.
// ---------------------------------------------------------------------------
template<int PACKED>
__global__ __launch_bounds__(256, 4)
void edge_fused(const unsigned* __restrict__ Pu,             // [N][256] uint pairs
                const float* __restrict__ ea,
                const unsigned short* __restrict__ eap,      // packed frags or null
                const int* __restrict__ srcI, const int* __restrict__ dstI,
                const unsigned short* __restrict__ WE,       // [2][128][64] this layer
                float* __restrict__ agg) {
    const int lane = threadIdx.x & 63;
    const int waveInBlk = threadIdx.x >> 6;
    const int quad = lane >> 4;
    const int l16 = lane & 15;
    const long nWaves = (long)gridDim.x * 4;
    const unsigned short* WEf = WE;
    const unsigned short* WEs = WE + 128 * 64;

    for (long chk = (long)blockIdx.x * 4 + waveInBlk; chk < NCHUNK; chk += nWaves) {
        const long e0 = chk * 16;
        int d16 = dstI[e0 + l16];
        int s16 = srcI[e0 + l16];

        s8v a0, a1;
        if (PACKED) {
            const s8v* af = (const s8v*)eap + chk * 128 + lane * 2;
            a0 = af[0];
            a1 = af[1];
        } else {
            const float* ar = ea + (e0 + l16) * (long)FE;
#pragma unroll
            for (int j = 0; j < 8; j++) a0[j] = (short)f2bf(ar[quad * 8 + j]);
            if (quad == 0) {
#pragma unroll
                for (int j = 0; j < 8; j++) a1[j] = (short)f2bf(ar[32 + j]);
            } else if (quad == 1) {
                a1 = (s8v)0;
                a1[0] = (short)f2bf(ar[40]);
                a1[1] = (short)0x3F80;          // bf16(1.0) bias column
            } else {
                a1 = (s8v)0;
            }
        }

        f4v accf[8], accs[8];
#pragma unroll
        for (int nt = 0; nt < 8; nt++) {
            int crow = nt * 16 + l16;
            s8v bf0 = *(const s8v*)(WEf + crow * 64 + quad * 8);
            s8v bf1 = *(const s8v*)(WEf + crow * 64 + 32 + quad * 8);
            f4v z = {0.f, 0.f, 0.f, 0.f};
            z = __builtin_amdgcn_mfma_f32_16x16x32_bf16(a0, bf0, z, 0, 0, 0);
            z = __builtin_amdgcn_mfma_f32_16x16x32_bf16(a1, bf1, z, 0, 0, 0);
            accf[nt] = z;
            s8v bs0 = *(const s8v*)(WEs + crow * 64 + quad * 8);
            s8v bs1 = *(const s8v*)(WEs + crow * 64 + 32 + quad * 8);
            f4v z2 = {0.f, 0.f, 0.f, 0.f};
            z2 = __builtin_amdgcn_mfma_f32_16x16x32_bf16(a0, bs0, z2, 0, 0, 0);
            z2 = __builtin_amdgcn_mfma_f32_16x16x32_bf16(a1, bs1, z2, 0, 0, 0);
            accs[nt] = z2;
        }

#pragma unroll
        for (int r = 0; r < 4; r++) {
            int el = quad * 4 + r;                 // edge row in D layout
            int dv = __shfl(d16, el);
            int sv = __shfl(s16, el);
            const uint4* pd4 = (const uint4*)(Pu + (long)dv * 256) + l16 * 2;
            const uint4* ps4 = (const uint4*)(Pu + (long)sv * 256 + 128) + l16 * 2;
            uint4 pd0 = pd4[0], pd1 = pd4[1];
            uint4 ps0 = ps4[0], ps1 = ps4[1];
            unsigned pdv[8] = {pd0.x, pd0.y, pd0.z, pd0.w, pd1.x, pd1.y, pd1.z, pd1.w};
            unsigned psv[8] = {ps0.x, ps0.y, ps0.z, ps0.w, ps1.x, ps1.y, ps1.z, ps1.w};
            float* ag = agg + (long)dv * CC;
#pragma unroll
            for (int nt = 0; nt < 8; nt++) {
                int c = nt * 16 + l16;
                float f = accf[nt][r] + bflo2f(pdv[nt]) + bflo2f(psv[nt]);
                float s = accs[nt][r] + bfhi2f(pdv[nt]) + bfhi2f(psv[nt]);
                float m = sigmoid_f(f) * softplus_f(s);
                atomicAdd(&ag[c], m);
            }
        }
    }
}

__global__ void residual_softplus(float* __restrict__ out, const float* __restrict__ agg) {
    int idx = blockIdx.x * blockDim.x + threadIdx.x;
    if (idx < NN * CC / 4) {
        float4 o = ((const float4*)out)[idx];
        float4 a = ((const float4*)agg)[idx];
        o.x = softplus_f(o.x + a.x);
        o.y = softplus_f(o.y + a.y);
        o.z = softplus_f(o.z + a.z);
        o.w = softplus_f(o.w + a.w);
        ((float4*)out)[idx] = o;
    }
}

__global__ void pool_accum(const float* __restrict__ post, const int* __restrict__ batch,
                           float* __restrict__ sums, float* __restrict__ cnt) {
    int idx = blockIdx.x * blockDim.x + threadIdx.x;
    if (idx >= NN * CC) return;
    int n = idx >> 7;
    int c = idx & 127;
    int g = batch[n];
    atomicAdd(&sums[g * CC + c], post[idx]);
    if (c == 0) atomicAdd(&cnt[g], 1.0f);
}

__global__ void pool_head(const float* __restrict__ sums, const float* __restrict__ cnt,
                          const float* __restrict__ Wout, const float* __restrict__ bout,
                          float* __restrict__ y) {
    int g = blockIdx.x;
    int c = threadIdx.x;  // 128
    float v = sums[g * CC + c] / fmaxf(cnt[g], 1.0f) * Wout[c];
#pragma unroll
    for (int off = 32; off > 0; off >>= 1) v += __shfl_down(v, off);
    __shared__ float red[2];
    if ((c & 63) == 0) red[c >> 6] = v;
    __syncthreads();
    if (c == 0) y[g] = red[0] + red[1] + bout[0];
}

extern "C" void kernel_launch(void* const* d_in, const int* in_sizes, int n_in,
                              void* d_out, int out_size, void* d_ws, size_t ws_size,
                              hipStream_t stream) {
    const float* x      = (const float*)d_in[0];
    const int*   eidx   = (const int*)d_in[1];
    const float* ea     = (const float*)d_in[2];
    const int*   batch  = (const int*)d_in[3];
    const float* W_pre  = (const float*)d_in[4];
    const float* b_pre  = (const float*)d_in[5];
    const float* Wf     = (const float*)d_in[6];
    const float* bf     = (const float*)d_in[7];
    const float* Ws     = (const float*)d_in[8];
    const float* bs     = (const float*)d_in[9];
    const float* W_post = (const float*)d_in[10];
    const float* b_post = (const float*)d_in[11];
    const float* W_out  = (const float*)d_in[12];
    const float* b_out  = (const float*)d_in[13];
    float* y = (float*)d_out;

    const int* srcI = eidx;        // edge_index[0] = src (x_j)
    const int* dstI = eidx + EE;   // edge_index[1] = dst (x_i)

    // workspace layout
    unsigned short* P_bf = (unsigned short*)d_ws;            // N*512 bf16 = 51.2MB
    float* out  = (float*)(P_bf + (size_t)NN * 512);         // N*128
    float* agg  = out + (size_t)NN * CC;                     // N*128
    float* WB   = agg + (size_t)NN * CC;                     // 128*512
    float* WT   = WB + 128 * 512;                            // 128*128
    float* sums = WT + 128 * 128;                            // G*128
    float* cnt  = sums + (size_t)GG * CC;                    // G
    unsigned short* WE = (unsigned short*)(cnt + GG);        // 3*2*128*64
    unsigned short* eap = WE + (size_t)LL * 2 * 128 * 64;    // NCHUNK*64*16 shorts
    float* post = (float*)P_bf;                              // reuse after layers

    size_t base_bytes = (size_t)((char*)eap - (char*)d_ws);
    size_t eap_bytes = (size_t)NCHUNK * 64 * 16 * sizeof(unsigned short);  // 204.8MB
    const bool packed = (ws_size >= base_bytes + eap_bytes);

    int rowTiles = (NN + 63) / 64;

    // pre-FC
    transpose_pad<<<(96 * 128 + 255) / 256, 256, 0, stream>>>(W_pre, WT, CC, FN, 96);
    gemm_rt<1, 0><<<rowTiles, 256, 0, stream>>>(x, WT, out, b_pre, NN, FN, FN, CC);

    build_WE<<<(LL * 2 * 128 * 64 + 255) / 256, 256, 0, stream>>>(Wf, Ws, bf, bs, WE);
    if (packed) {
        long nt = (long)NCHUNK * 64;
        pack_ea<<<(int)((nt + 255) / 256), 256, 0, stream>>>(ea, eap);
    }

    for (int l = 0; l < LL; l++) {
        const float* Wfl = Wf + (size_t)l * CC * ZDIM;
        const float* Wsl = Ws + (size_t)l * CC * ZDIM;
        build_WB<<<(128 * 512 + 255) / 256, 256, 0, stream>>>(Wfl, Wsl, WB);
        gemm_rt<0, 1><<<rowTiles * 4, 256, 0, stream>>>(out, WB, (float*)P_bf,
                                                        nullptr, NN, CC, CC, 512);
        hipMemsetAsync(agg, 0, (size_t)NN * CC * sizeof(float), stream);
        const unsigned short* WEl = WE + (size_t)l * 2 * 128 * 64;
        if (packed)
            edge_fused<1><<<4096, 256, 0, stream>>>((const unsigned*)P_bf, ea, eap,
                                                    srcI, dstI, WEl, agg);
        else
            edge_fused<0><<<4096, 256, 0, stream>>>((const unsigned*)P_bf, ea, nullptr,
                                                    srcI, dstI, WEl, agg);
        residual_softplus<<<(NN * CC / 4 + 255) / 256, 256, 0, stream>>>(out, agg);
    }

    // post-FC
    transpose_pad<<<(128 * 128 + 255) / 256, 256, 0, stream>>>(W_post, WT, CC, CC, CC);
    gemm_rt<1, 0><<<rowTiles, 256, 0, stream>>>(out, WT, post, b_post, NN, CC, CC, CC);

    // global mean pool + head
    hipMemsetAsync(sums, 0, ((size_t)GG * CC + GG) * sizeof(float), stream);
    pool_accum<<<(NN * CC + 255) / 256, 256, 0, stream>>>(post, batch, sums, cnt);
    pool_head<<<GG, 128, 0, stream>>>(sums, cnt, W_out, b_out, y);
}